// Round 2
// baseline (3538.761 us; speedup 1.0000x reference)
//
#include <hip/hip_runtime.h>
#include <cstdint>
#include <cstddef>

#define TT 128
#define HID 256
#define GG4 1024
#define GG3 768
#define MAXLV 64
#define NBS 32   // lstm blocks per direction

__device__ __forceinline__ float sigf(float x){ return 1.f/(1.f+__expf(-x)); }
__device__ __forceinline__ float tanh_(float x){
  float cx = fminf(fmaxf(x,-15.f),15.f);
  float e = __expf(2.f*cx);
  return (e-1.f)/(e+1.f);
}

// Inter-block barrier: fresh zeroed counter per use (replay-safe), bounded spin.
__device__ __forceinline__ void grp_barrier(int* cnt, int expected){
  __syncthreads();
  if (threadIdx.x == 0){
    __hip_atomic_fetch_add(cnt, 1, __ATOMIC_ACQ_REL, __HIP_MEMORY_SCOPE_AGENT);
    long it = 0;
    while (__hip_atomic_load(cnt, __ATOMIC_RELAXED, __HIP_MEMORY_SCOPE_AGENT) < expected){
      __builtin_amdgcn_s_sleep(1);
      if (++it > 60000000L) break;   // give up instead of hanging (wrong answer > timeout)
    }
    __builtin_amdgcn_fence(__ATOMIC_ACQUIRE, "agent");
  }
  __syncthreads();
}

// ---------------- embedding gather: x[m][e] = emb[ids[m]][e] ----------------
__global__ __launch_bounds__(256) void gather_x_kernel(
    const int* __restrict__ ids, const float* __restrict__ emb, float* __restrict__ x)
{
  int it = blockIdx.x*256 + threadIdx.x;        // item = m*75 + q  (300 = 75 float4)
  if (it >= 8192*75) return;
  int m = it / 75, q = (it % 75) * 4;
  int id = ids[m];
  *(float4*)&x[(size_t)m*300 + q] = *(const float4*)&emb[(size_t)id*300 + q];
}

// ---------------- generic tiled GEMM: C[m][n] = A[m][:]·W[n][:] (+bias) -----
// PERM: out row = (m%128)*64 + m/128   (lay xg out as [t][b][gates])
template<bool PERM, bool BIAS>
__global__ __launch_bounds__(256) void gemm_kernel(
    const float* __restrict__ A, const float* __restrict__ W,
    const float* __restrict__ bias, float* __restrict__ C,
    int M, int Nn, int K)
{
  __shared__ float As[16][64];
  __shared__ float Ws[16][64];
  const int tid = threadIdx.x;
  const int m0 = blockIdx.x * 64, n0 = blockIdx.y * 64;
  const int tx = tid & 15, ty = tid >> 4;
  const int lr = tid >> 2, lk = (tid & 3) << 2;
  float acc[4][4] = {};
  for (int k0 = 0; k0 < K; k0 += 16) {
    float4 av = make_float4(0,0,0,0), wv = make_float4(0,0,0,0);
    const int gm = m0 + lr, gn = n0 + lr;
    if (gm < M) {
      if (k0 + lk + 4 <= K) av = *(const float4*)&A[(size_t)gm*K + k0 + lk];
      else {
        float t_[4] = {0,0,0,0};
        for (int j = 0; j < 4; j++) if (k0+lk+j < K) t_[j] = A[(size_t)gm*K + k0+lk+j];
        av = make_float4(t_[0],t_[1],t_[2],t_[3]);
      }
    }
    if (gn < Nn) {
      if (k0 + lk + 4 <= K) wv = *(const float4*)&W[(size_t)gn*K + k0 + lk];
      else {
        float t_[4] = {0,0,0,0};
        for (int j = 0; j < 4; j++) if (k0+lk+j < K) t_[j] = W[(size_t)gn*K + k0+lk+j];
        wv = make_float4(t_[0],t_[1],t_[2],t_[3]);
      }
    }
    __syncthreads();
    As[lk+0][lr]=av.x; As[lk+1][lr]=av.y; As[lk+2][lr]=av.z; As[lk+3][lr]=av.w;
    Ws[lk+0][lr]=wv.x; Ws[lk+1][lr]=wv.y; Ws[lk+2][lr]=wv.z; Ws[lk+3][lr]=wv.w;
    __syncthreads();
#pragma unroll
    for (int k = 0; k < 16; k++) {
      const float4 a = *(const float4*)&As[k][ty<<2];
      const float4 b = *(const float4*)&Ws[k][tx<<2];
      float a_[4] = {a.x,a.y,a.z,a.w};
      float b_[4] = {b.x,b.y,b.z,b.w};
#pragma unroll
      for (int i = 0; i < 4; i++)
#pragma unroll
        for (int j = 0; j < 4; j++) acc[i][j] += a_[i]*b_[j];
    }
  }
  float4 bv = make_float4(0,0,0,0);
  if (BIAS) bv = *(const float4*)&bias[n0 + (tx<<2)];
#pragma unroll
  for (int i = 0; i < 4; i++) {
    int gm = m0 + (ty<<2) + i;
    if (gm >= M) continue;
    int orow = PERM ? (((gm & 127) << 6) | (gm >> 7)) : gm;
    float4 o = make_float4(acc[i][0]+bv.x, acc[i][1]+bv.y, acc[i][2]+bv.z, acc[i][3]+bv.w);
    *(float4*)&C[(size_t)orow*Nn + n0 + (tx<<2)] = o;
  }
}

// ---------------- bidirectional LSTM recurrence ------------------------------
// 64 blocks: dir = blk>>5, slice = blk&31 owns 8 hidden units (32 Whh rows in LDS).
// h slabs: hf[s] = fwd state after step s-1 (slab0 = 0); hb[t] = bwd state at t (slab128 = 0).
__global__ __launch_bounds__(256) void lstm_kernel(
    const float* __restrict__ xgf, const float* __restrict__ xgb,
    const float* __restrict__ whhf, const float* __restrict__ whhb,
    const int* __restrict__ lengths,
    float* __restrict__ hf, float* __restrict__ hb,
    int* __restrict__ cnt)
{
  const int dir = blockIdx.x >> 5;
  const int sl  = blockIdx.x & 31;
  const float* __restrict__ xg  = dir ? xgb : xgf;
  const float* __restrict__ whh = dir ? whhb : whhf;
  float* __restrict__ hbuf = dir ? hb : hf;
  int* mycnt = cnt + dir * TT;
  const int tid = threadIdx.x;
  const int r  = tid & 63;
  const int u2 = tid >> 6;          // 0..3
  const int u0 = sl << 3;
  const int ua = u0 + (u2 << 1);    // first of this thread's 2 units

  __shared__ float wl[32][256];     // rows: g*8+uu -> whh[g*256+u0+uu][:]
  for (int i = tid; i < 32*64; i += 256) {
    const int row = i >> 6, q = (i & 63) << 2;
    const int g = row >> 3, uu = row & 7;
    *(float4*)&wl[row][q] = *(const float4*)&whh[(size_t)((g << 8) + u0 + uu)*256 + q];
  }
  __syncthreads();

  const int len_r = lengths[r];
  float c0 = 0.f, c1 = 0.f;
  for (int s = 0; s < TT; s++) {
    const int t   = dir ? (TT - 1 - s) : s;
    const int rsl = dir ? (t + 1) : t;      // read slab
    const int wsl = dir ? t : (t + 1);      // write slab
    float acc[8] = {0,0,0,0,0,0,0,0};
    const float* __restrict__ hrow = hbuf + ((size_t)rsl*64 + r)*256;
#pragma unroll 4
    for (int k4 = 0; k4 < 64; k4++) {
      const float4 hv = *(const float4*)&hrow[k4 << 2];
#pragma unroll
      for (int g = 0; g < 4; g++) {
        const float4 w0 = *(const float4*)&wl[(g<<3) + (u2<<1) + 0][k4 << 2];
        const float4 w1 = *(const float4*)&wl[(g<<3) + (u2<<1) + 1][k4 << 2];
        acc[(g<<1)+0] += hv.x*w0.x + hv.y*w0.y + hv.z*w0.z + hv.w*w0.w;
        acc[(g<<1)+1] += hv.x*w1.x + hv.y*w1.y + hv.z*w1.z + hv.w*w1.w;
      }
    }
    const bool act = dir ? (t < len_r) : true;
    if (act) {
      const float* __restrict__ xrow = xg + ((size_t)t*64 + r)*GG4;
      const float2 xi = *(const float2*)&xrow[0*256 + ua];
      const float2 xf = *(const float2*)&xrow[1*256 + ua];
      const float2 xu = *(const float2*)&xrow[2*256 + ua];
      const float2 xo = *(const float2*)&xrow[3*256 + ua];
      c0 = sigf(xf.x + acc[2])*c0 + sigf(xi.x + acc[0])*tanh_(xu.x + acc[4]);
      c1 = sigf(xf.y + acc[3])*c1 + sigf(xi.y + acc[1])*tanh_(xu.y + acc[5]);
      const float h0 = sigf(xo.x + acc[6])*tanh_(c0);
      const float h1 = sigf(xo.y + acc[7])*tanh_(c1);
      *(float2*)&hbuf[((size_t)wsl*64 + r)*256 + ua] = make_float2(h0, h1);
    }
    if (s < TT-1) grp_barrier(&mycnt[s], NBS);
  }
}

// ---------------- hx = concat(h_f[tok], h_b[tok]) ----------------------------
__global__ __launch_bounds__(256) void gather_hx_kernel(
    const int* __restrict__ tok, const float* __restrict__ hf,
    const float* __restrict__ hb, float* __restrict__ hx, int Nn)
{
  int it = blockIdx.x*256 + threadIdx.x;        // item = n*128 + q (512/4 quads)
  if (it >= Nn*128) return;
  int n = it >> 7, q = it & 127;
  int tk = tok[n];
  int b = tk >> 7, t = tk & 127;
  float4 v;
  if (q < 64) v = *(const float4*)&hf[((size_t)(t+1)*64 + b)*256 + (q<<2)];
  else        v = *(const float4*)&hb[((size_t)t*64 + b)*256 + ((q-64)<<2)];
  *(float4*)&hx[(size_t)n*512 + (q<<2)] = v;
}

// ---------------- counting sort of edges by child level ----------------------
__global__ __launch_bounds__(1024) void sort_edges_kernel(
    const int* __restrict__ child_idx, const int* __restrict__ node_level,
    int* __restrict__ elist, int* __restrict__ lvloff, int E)
{
  __shared__ int hist[MAXLV];
  __shared__ int cur[MAXLV];
  int tid = threadIdx.x;
  if (tid < MAXLV) hist[tid] = 0;
  __syncthreads();
  for (int e = tid; e < E; e += 1024) {
    int lv = node_level[child_idx[e]];
    lv = lv < MAXLV-1 ? lv : MAXLV-1;
    atomicAdd(&hist[lv], 1);
  }
  __syncthreads();
  if (tid == 0) {
    int s = 0;
    for (int l = 0; l < MAXLV; l++) { cur[l] = s; lvloff[l] = s; s += hist[l]; }
    lvloff[MAXLV] = s;
  }
  __syncthreads();
  for (int e = tid; e < E; e += 1024) {
    int lv = node_level[child_idx[e]];
    lv = lv < MAXLV-1 ? lv : MAXLV-1;
    int pos = atomicAdd(&cur[lv], 1);
    elist[pos] = e;
  }
}

// ---------------- tree (ChildSum-ish) level loop -----------------------------
__global__ __launch_bounds__(256) void tree_kernel(
    const int* __restrict__ nlv_ptr, const int* __restrict__ node_level,
    const int* __restrict__ child_idx, const int* __restrict__ parent_idx,
    const int* __restrict__ elist, const int* __restrict__ lvloff,
    const float* __restrict__ Uiou, const float* __restrict__ Uf,
    const float* __restrict__ biou, const float* __restrict__ buf_,
    float* __restrict__ iou, float* __restrict__ cnode,
    float* __restrict__ cred, float* __restrict__ hout,
    int* __restrict__ cnt, int Nn)
{
  int n_lv = nlv_ptr[0];
  if (n_lv > MAXLV) n_lv = MAXLV;
  const int tid = threadIdx.x;
  __shared__ float hs[8][256];
  __shared__ float cs[8][256];
  __shared__ int pidx[8];
  for (int l = 0; l < n_lv; l++) {
    // Phase A: apply node func for nodes at level l
    for (int it = blockIdx.x*256 + tid; it < Nn*64; it += gridDim.x*256) {
      const int n = it >> 6, q = (it & 63) << 2;
      if (node_level[n] != l) continue;
      const float4 iv = *(const float4*)&iou[(size_t)n*GG3 + q];
      const float4 ov = *(const float4*)&iou[(size_t)n*GG3 + 256 + q];
      const float4 uv = *(const float4*)&iou[(size_t)n*GG3 + 512 + q];
      const float4 bi = *(const float4*)&biou[q];
      const float4 bo = *(const float4*)&biou[256 + q];
      const float4 bu = *(const float4*)&biou[512 + q];
      const float4 cr = *(const float4*)&cred[(size_t)n*HID + q];
      float cn[4], hn[4];
      cn[0] = sigf(iv.x+bi.x)*tanh_(uv.x+bu.x) + cr.x;
      cn[1] = sigf(iv.y+bi.y)*tanh_(uv.y+bu.y) + cr.y;
      cn[2] = sigf(iv.z+bi.z)*tanh_(uv.z+bu.z) + cr.z;
      cn[3] = sigf(iv.w+bi.w)*tanh_(uv.w+bu.w) + cr.w;
      hn[0] = sigf(ov.x+bo.x)*tanh_(cn[0]);
      hn[1] = sigf(ov.y+bo.y)*tanh_(cn[1]);
      hn[2] = sigf(ov.z+bo.z)*tanh_(cn[2]);
      hn[3] = sigf(ov.w+bo.w)*tanh_(cn[3]);
      *(float4*)&cnode[(size_t)n*HID + q] = make_float4(cn[0],cn[1],cn[2],cn[3]);
      *(float4*)&hout [(size_t)n*HID + q] = make_float4(hn[0],hn[1],hn[2],hn[3]);
    }
    grp_barrier(&cnt[2*l], gridDim.x);
    // Phase B: messages from level-l children to parents
    const int e0 = lvloff[l], e1 = lvloff[l+1];
    const int nb = (e1 - e0 + 7) >> 3;
    for (int bat = blockIdx.x; bat < nb; bat += gridDim.x) {
      const int base = e0 + (bat << 3);
      const int c8 = (e1 - base) < 8 ? (e1 - base) : 8;
      __syncthreads();
      for (int li = tid; li < 1024; li += 256) {
        const int j = li >> 7, q = li & 127;
        if (j < c8) {
          const int e = elist[base + j];
          const int ch = child_idx[e];
          if (q < 64) *(float4*)&hs[j][q<<2]      = *(const float4*)&hout [(size_t)ch*HID + (q<<2)];
          else        *(float4*)&cs[j][(q-64)<<2] = *(const float4*)&cnode[(size_t)ch*HID + ((q-64)<<2)];
        }
      }
      if (tid < 8) pidx[tid] = (tid < c8) ? parent_idx[elist[base + tid]] : -1;
      __syncthreads();
      float acc[8][4] = {};
      const int qq = tid;
      const float* __restrict__ w0 = (qq < 192)
          ? (Uiou + (size_t)(qq<<2)*HID)
          : (Uf   + (size_t)((qq-192)<<2)*HID);
#pragma unroll 2
      for (int k4 = 0; k4 < 64; k4++) {
        const int kof = k4 << 2;
        const float4 a0 = *(const float4*)&w0[kof];
        const float4 a1 = *(const float4*)&w0[HID   + kof];
        const float4 a2 = *(const float4*)&w0[2*HID + kof];
        const float4 a3 = *(const float4*)&w0[3*HID + kof];
#pragma unroll
        for (int j = 0; j < 8; j++) {
          const float4 hv = *(const float4*)&hs[j][kof];
          acc[j][0] += hv.x*a0.x + hv.y*a0.y + hv.z*a0.z + hv.w*a0.w;
          acc[j][1] += hv.x*a1.x + hv.y*a1.y + hv.z*a1.z + hv.w*a1.w;
          acc[j][2] += hv.x*a2.x + hv.y*a2.y + hv.z*a2.z + hv.w*a2.w;
          acc[j][3] += hv.x*a3.x + hv.y*a3.y + hv.z*a3.z + hv.w*a3.w;
        }
      }
      if (qq < 192) {
#pragma unroll
        for (int j = 0; j < 8; j++) {
          const int p = pidx[j];
          if (p < 0) continue;
          float* dst = &iou[(size_t)p*GG3 + (qq<<2)];
          unsafeAtomicAdd(dst+0, acc[j][0]);
          unsafeAtomicAdd(dst+1, acc[j][1]);
          unsafeAtomicAdd(dst+2, acc[j][2]);
          unsafeAtomicAdd(dst+3, acc[j][3]);
        }
      } else {
        const int r0 = (qq-192) << 2;
        const float4 bv = *(const float4*)&buf_[r0];
#pragma unroll
        for (int j = 0; j < 8; j++) {
          const int p = pidx[j];
          if (p < 0) continue;
          float* dst = &cred[(size_t)p*HID + r0];
          unsafeAtomicAdd(dst+0, sigf(acc[j][0]+bv.x)*cs[j][r0+0]);
          unsafeAtomicAdd(dst+1, sigf(acc[j][1]+bv.y)*cs[j][r0+1]);
          unsafeAtomicAdd(dst+2, sigf(acc[j][2]+bv.z)*cs[j][r0+2]);
          unsafeAtomicAdd(dst+3, sigf(acc[j][3]+bv.w)*cs[j][r0+3]);
        }
      }
    }
    grp_barrier(&cnt[2*l+1], gridDim.x);
  }
}

// ---------------- launch ------------------------------------------------------
extern "C" void kernel_launch(void* const* d_in, const int* in_sizes, int n_in,
                              void* d_out, int out_size, void* d_ws, size_t ws_size,
                              hipStream_t stream)
{
  const int*   embed_ids = (const int*)d_in[0];
  const int*   lengths   = (const int*)d_in[1];
  const int*   child_idx = (const int*)d_in[2];
  const int*   parent_idx= (const int*)d_in[3];
  const int*   tok_idx   = (const int*)d_in[4];
  const int*   node_level= (const int*)d_in[5];
  const int*   nlv       = (const int*)d_in[6];
  const float* emb  = (const float*)d_in[7];
  const float* wihf = (const float*)d_in[8];
  const float* whhf = (const float*)d_in[9];
  const float* bf   = (const float*)d_in[10];
  const float* wihb = (const float*)d_in[11];
  const float* whhb = (const float*)d_in[12];
  const float* bb   = (const float*)d_in[13];
  const float* Wiou = (const float*)d_in[14];
  const float* Uiou = (const float*)d_in[15];
  const float* biou = (const float*)d_in[16];
  const float* Uf   = (const float*)d_in[17];
  const float* buf_ = (const float*)d_in[18];
  const int E  = in_sizes[2];
  const int Nn = in_sizes[4];
  float* hout = (float*)d_out;

  char* w = (char*)d_ws;
  size_t off = 0;
  auto take = [&](size_t bytes) -> char* {
    char* p = w + off;
    off += (bytes + 255) & ~(size_t)255;
    return p;
  };
  int*   cnt   = (int*)  take(8192);                       // zeroed
  float* hf    = (float*)take((size_t)129*64*256*4);       // zeroed
  float* hb    = (float*)take((size_t)129*64*256*4);       // zeroed
  float* cred  = (float*)take((size_t)Nn*HID*4);           // zeroed
  size_t zero_end = off;
  float* x     = (float*)take((size_t)8192*300*4);
  float* xgf   = (float*)take((size_t)8192*1024*4);
  float* xgb   = (float*)take((size_t)8192*1024*4);
  float* hx    = (float*)take((size_t)Nn*512*4);
  float* iou   = (float*)take((size_t)Nn*GG3*4);
  float* cnode = (float*)take((size_t)Nn*HID*4);
  int*   elist = (int*)  take((size_t)E*4);
  int*   lvloff= (int*)  take((size_t)(MAXLV+1)*4);
  (void)ws_size; (void)n_in; (void)out_size;

  hipMemsetAsync(d_ws, 0, zero_end, stream);
  gather_x_kernel<<<(8192*75 + 255)/256, 256, 0, stream>>>(embed_ids, emb, x);
  gemm_kernel<true,true><<<dim3(8192/64, 1024/64), 256, 0, stream>>>(x, wihf, bf, xgf, 8192, 1024, 300);
  gemm_kernel<true,true><<<dim3(8192/64, 1024/64), 256, 0, stream>>>(x, wihb, bb, xgb, 8192, 1024, 300);
  lstm_kernel<<<64, 256, 0, stream>>>(xgf, xgb, whhf, whhb, lengths, hf, hb, cnt);
  gather_hx_kernel<<<(Nn*128 + 255)/256, 256, 0, stream>>>(tok_idx, hf, hb, hx, Nn);
  gemm_kernel<false,false><<<dim3((Nn+63)/64, GG3/64), 256, 0, stream>>>(hx, Wiou, nullptr, iou, Nn, GG3, 512);
  sort_edges_kernel<<<1, 1024, 0, stream>>>(child_idx, node_level, elist, lvloff, E);
  tree_kernel<<<64, 256, 0, stream>>>(nlv, node_level, child_idx, parent_idx, elist, lvloff,
                                      Uiou, Uf, biou, buf_, iou, cnode, cred, hout, cnt + 1024, Nn);
}